// Round 8
// baseline (233.461 us; speedup 1.0000x reference)
//
#include <hip/hip_runtime.h>

#define N_NODES 100000
#define IN_DIM 128
#define HID_DIM 128
#define GM 64         // nodes per block in fused gather+GEMM
#define NB 196        // buckets (512 nodes each): b = dst >> 9
#define BCAP 17200    // per-bucket edge capacity (mean 16384, +6 sigma)
#define TILE 4096     // edges per P1 tile

typedef __attribute__((ext_vector_type(8))) short bf16x8;
typedef __attribute__((ext_vector_type(4))) float f32x4;

__device__ inline ushort bf16rne(float x) {
    uint u = __float_as_uint(x);
    return (ushort)((u + 0x7FFFu + ((u >> 16) & 1u)) >> 16);
}

// ---- P1: bin edges by dst>>9; payload packed to 4 B: src | (local_dst<<17) ----
__global__ __launch_bounds__(256) void p1_bin_kernel(
    const int* __restrict__ src, const int* __restrict__ dst,
    int* __restrict__ bcursor, uint* __restrict__ binned, int nE) {
    __shared__ uint staged[TILE];    // 16 KB
    __shared__ uchar bid[TILE];      // 4 KB
    __shared__ int cnt[256];
    __shared__ int scn[256];
    __shared__ int cur[256];
    __shared__ int gbase[256];
    int t = threadIdx.x;
    int e0 = blockIdx.x * TILE;
    int tilecnt = nE - e0; if (tilecnt > TILE) tilecnt = TILE;

    cnt[t] = 0;
    __syncthreads();

    int es[16], ed[16];
    int vk[4];
#pragma unroll
    for (int k = 0; k < 4; k++) {
        int base = e0 + (k * 256 + t) * 4;
        vk[k] = (base < nE);
        if (vk[k]) {
            int4 s4 = *(const int4*)(src + base);
            int4 d4 = *(const int4*)(dst + base);
            es[k*4+0]=s4.x; es[k*4+1]=s4.y; es[k*4+2]=s4.z; es[k*4+3]=s4.w;
            ed[k*4+0]=d4.x; ed[k*4+1]=d4.y; ed[k*4+2]=d4.z; ed[k*4+3]=d4.w;
        }
    }
#pragma unroll
    for (int k = 0; k < 4; k++)
        if (vk[k]) {
#pragma unroll
            for (int j = 0; j < 4; j++) atomicAdd(&cnt[ed[k*4+j] >> 9], 1);
        }
    __syncthreads();
    scn[t] = cnt[t];
    __syncthreads();
    for (int d = 1; d < 256; d <<= 1) {
        int v = (t >= d) ? scn[t - d] : 0;
        __syncthreads();
        scn[t] += v;
        __syncthreads();
    }
    int excl = scn[t] - cnt[t];
    __syncthreads();
    scn[t] = excl;
    cur[t] = excl;
    if (t < NB) gbase[t] = atomicAdd(&bcursor[t], cnt[t]);
    __syncthreads();
#pragma unroll
    for (int k = 0; k < 4; k++)
        if (vk[k]) {
#pragma unroll
            for (int j = 0; j < 4; j++) {
                int d = ed[k*4+j];
                int b = d >> 9;
                int r = atomicAdd(&cur[b], 1);
                staged[r] = (uint)es[k*4+j] | ((uint)(d & 511) << 17);
                bid[r] = (uchar)b;
            }
        }
    __syncthreads();
    for (int i = t; i < tilecnt; i += 256) {
        uint p = staged[i];
        int b = bid[i];
        int off = gbase[b] + (i - scn[b]);
        if (off < BCAP) binned[(long)b * BCAP + off] = p;
    }
}

// ---- P2: one block per bucket; build exact CSR in LDS; emits norm ----
__global__ __launch_bounds__(512) void p2_fill_kernel(
    const uint* __restrict__ binned, const int* __restrict__ bcursor,
    int* __restrict__ lists, int* __restrict__ off_g, int* __restrict__ degi,
    float* __restrict__ norm, int N) {
    __shared__ int deg_l[512];
    __shared__ int off_l[512];
    __shared__ int cur_l[512];
    __shared__ int stage[BCAP];   // 68.8 KB
    int b = blockIdx.x;
    int t = threadIdx.x;
    int cnt = bcursor[b]; if (cnt > BCAP) cnt = BCAP;
    const uint* eb = binned + (long)b * BCAP;
    int d0 = b << 9;

    deg_l[t] = 0;
    cur_l[t] = 0;
    __syncthreads();
    for (int i = t; i < cnt; i += 512) atomicAdd(&deg_l[eb[i] >> 17], 1);
    __syncthreads();
    off_l[t] = deg_l[t];
    __syncthreads();
    for (int d = 1; d < 512; d <<= 1) {
        int v = (t >= d) ? off_l[t - d] : 0;
        __syncthreads();
        off_l[t] += v;
        __syncthreads();
    }
    int excl = off_l[t] - deg_l[t];
    int node = d0 + t;
    if (node < N) {
        int dg = deg_l[t];
        degi[node] = dg;
        off_g[node] = b * BCAP + excl;
        norm[node] = rsqrtf((float)(dg < 1 ? 1 : dg));
    }
    __syncthreads();
    off_l[t] = excl;
    __syncthreads();
    for (int i = t; i < cnt; i += 512) {
        uint p = eb[i];
        int li = p >> 17;
        int pos = off_l[li] + atomicAdd(&cur_l[li], 1);
        stage[pos] = (int)(p & 0x1FFFFu);
    }
    __syncthreads();
    for (int i = t; i < cnt; i += 512) lists[(long)b * BCAP + i] = stage[i];
}

// ---- prep: hn[n] = bf16(h[n] * norm[n]); row N = zeros ----
__global__ void prep_kernel(const float* __restrict__ h, const float* __restrict__ norm,
                            ushort* __restrict__ hn, int N) {
    int t = blockIdx.x * blockDim.x + threadIdx.x;
    int node = t >> 4;
    if (node > N) return;
    uint4 o = make_uint4(0, 0, 0, 0);
    if (node < N) {
        int c = (t & 15) * 8;
        float nm = norm[node];
        const float* p = h + (long)node * IN_DIM + c;
        float4 a = ((const float4*)p)[0];
        float4 bb = ((const float4*)p)[1];
        float v[8] = {a.x, a.y, a.z, a.w, bb.x, bb.y, bb.z, bb.w};
        uint r[8];
#pragma unroll
        for (int i = 0; i < 8; i++) r[i] = (uint)bf16rne(v[i] * nm);
        o.x = r[0] | (r[1] << 16);
        o.y = r[2] | (r[3] << 16);
        o.z = r[4] | (r[5] << 16);
        o.w = r[6] | (r[7] << 16);
    }
    ((uint4*)hn)[t] = o;
}

// ---- W [256][128] fp32 -> wt [128][256] bf16 (transposed) ----
__global__ void wconv_kernel(const float* __restrict__ W, ushort* __restrict__ wt) {
    int t = blockIdx.x * blockDim.x + threadIdx.x;  // 32768
    int j = t >> 8, k = t & 255;
    wt[t] = bf16rne(W[k * HID_DIM + j]);
}

// ---- fused gather + MFMA GEMM + L2norm; 512 threads (8 waves), 64 nodes ----
// Wave w gathers nodes w*8..w*8+7 (agg-half -> LDS bf16), owns GEMM cols 16w..16w+15.
__global__ __launch_bounds__(512) void fused_kernel(
    const ushort* __restrict__ hn, const int* __restrict__ lists,
    const int* __restrict__ off_g, const int* __restrict__ degi,
    const float* __restrict__ norm, const ushort* __restrict__ wt,
    const float* __restrict__ b, float* __restrict__ out, int N) {
    int t = threadIdx.x;
    int w = t >> 6;
    int l = t & 63;
    int n0 = blockIdx.x * GM;

    __shared__ __align__(16) ushort rows[GM][264];  // 33.8 KB; 528 B stride (2-way banks, free)
    __shared__ float partial[8][GM];                // 2 KB

    // Phase A: h-half (cols 0..127) = hn * (1/norm)  (bf16 source, L2/L3-warm)
    for (int f = t; f < GM * 16; f += 512) {
        int m = f >> 4, c = (f & 15) * 8;
        int n = n0 + m;
        uint4 o = make_uint4(0, 0, 0, 0);
        if (n < N) {
            float rn = 1.0f / norm[n];
            uint4 v = *(const uint4*)(hn + (long)n * IN_DIM + c);
            uint r[8];
            float f0 = __uint_as_float(v.x << 16) * rn;
            float f1 = __uint_as_float(v.x & 0xFFFF0000u) * rn;
            float f2 = __uint_as_float(v.y << 16) * rn;
            float f3 = __uint_as_float(v.y & 0xFFFF0000u) * rn;
            float f4 = __uint_as_float(v.z << 16) * rn;
            float f5 = __uint_as_float(v.z & 0xFFFF0000u) * rn;
            float f6 = __uint_as_float(v.w << 16) * rn;
            float f7 = __uint_as_float(v.w & 0xFFFF0000u) * rn;
            r[0] = bf16rne(f0); r[1] = bf16rne(f1); r[2] = bf16rne(f2); r[3] = bf16rne(f3);
            r[4] = bf16rne(f4); r[5] = bf16rne(f5); r[6] = bf16rne(f6); r[7] = bf16rne(f7);
            o.x = r[0] | (r[1] << 16);
            o.y = r[2] | (r[3] << 16);
            o.z = r[4] | (r[5] << 16);
            o.w = r[6] | (r[7] << 16);
        }
        *(uint4*)&rows[m][c] = o;
    }

    // Phase B: gather agg-half (cols 128..255); 8 nodes per wave, 4 loads in flight
    int quarter = l >> 4;
    int col = (l & 15) * 8;
    for (int i = 0; i < 8; i++) {
        int m = w * 8 + i;
        int node = n0 + m;
        float acc[8];
#pragma unroll
        for (int q = 0; q < 8; q++) acc[q] = 0.0f;
        int deg = 0;
        const int* mylist = lists;
        if (node < N) { deg = degi[node]; mylist = lists + off_g[node]; }
        for (int base = 0; base < deg; base += 64) {
            int cnt = deg - base; if (cnt > 64) cnt = 64;
            int myidx = (l < cnt) ? mylist[base + l] : 0;
            for (int j = 0; j < cnt; j += 16) {
                uint4 v[4];
#pragma unroll
                for (int u = 0; u < 4; u++) {
                    int sel = j + 4 * u + quarter;
                    int selc = sel < cnt ? sel : cnt - 1;
                    int s = __shfl(myidx, selc);
                    if (sel >= cnt) s = N;       // zero row
                    v[u] = *(const uint4*)(hn + (long)s * IN_DIM + col);
                }
#pragma unroll
                for (int u = 0; u < 4; u++) {
                    acc[0] += __uint_as_float(v[u].x << 16);
                    acc[1] += __uint_as_float(v[u].x & 0xFFFF0000u);
                    acc[2] += __uint_as_float(v[u].y << 16);
                    acc[3] += __uint_as_float(v[u].y & 0xFFFF0000u);
                    acc[4] += __uint_as_float(v[u].z << 16);
                    acc[5] += __uint_as_float(v[u].z & 0xFFFF0000u);
                    acc[6] += __uint_as_float(v[u].w << 16);
                    acc[7] += __uint_as_float(v[u].w & 0xFFFF0000u);
                }
            }
        }
#pragma unroll
        for (int q = 0; q < 8; q++) {
            acc[q] += __shfl_xor(acc[q], 16);
            acc[q] += __shfl_xor(acc[q], 32);
        }
        if (quarter == 0) {
            float nm = (node < N) ? norm[node] : 0.0f;
            uint r[8];
#pragma unroll
            for (int q = 0; q < 8; q++) r[q] = (uint)bf16rne(acc[q] * nm);
            uint4 o;
            o.x = r[0] | (r[1] << 16);
            o.y = r[2] | (r[3] << 16);
            o.z = r[4] | (r[5] << 16);
            o.w = r[6] | (r[7] << 16);
            *(uint4*)&rows[m][IN_DIM + col] = o;
        }
    }

    // W slab into registers (16 cols per wave; L2-resident wt)
    bf16x8 bfrag[8];
    {
        int colA = 16 * w + (l & 15);
        int ko = (l >> 4) * 8;
#pragma unroll
        for (int kt = 0; kt < 8; kt++)
            bfrag[kt] = *(const bf16x8*)(wt + (long)colA * 256 + kt * 32 + ko);
    }

    float bj = b[16 * w + (l & 15)];
    f32x4 acc[4];
#pragma unroll
    for (int mt = 0; mt < 4; mt++) acc[mt] = (f32x4){bj, bj, bj, bj};
    __syncthreads();

    // K loop: 8 steps of 32
#pragma unroll
    for (int kt = 0; kt < 8; kt++) {
        int kbyte = kt * 64 + (l >> 4) * 16;
#pragma unroll
        for (int mt = 0; mt < 4; mt++) {
            int row = mt * 16 + (l & 15);
            bf16x8 a = *(const bf16x8*)((const char*)&rows[row][0] + kbyte);
            acc[mt] = __builtin_amdgcn_mfma_f32_16x16x32_bf16(a, bfrag[kt], acc[mt], 0, 0, 0);
        }
    }

    // per-row sum of squares within this wave's 16 cols: C/D col=l&15, row=(l>>4)*4+i
#pragma unroll
    for (int mt = 0; mt < 4; mt++)
#pragma unroll
        for (int i = 0; i < 4; i++) {
            float s = acc[mt][i] * acc[mt][i];
            s += __shfl_xor(s, 1);
            s += __shfl_xor(s, 2);
            s += __shfl_xor(s, 4);
            s += __shfl_xor(s, 8);
            if ((l & 15) == 0) partial[w][mt * 16 + (l >> 4) * 4 + i] = s;
        }
    __syncthreads();

#pragma unroll
    for (int mt = 0; mt < 4; mt++)
#pragma unroll
        for (int i = 0; i < 4; i++) {
            int r = mt * 16 + (l >> 4) * 4 + i;
            int n = n0 + r;
            if (n < N) {
                float ssum = partial[0][r] + partial[1][r] + partial[2][r] + partial[3][r]
                           + partial[4][r] + partial[5][r] + partial[6][r] + partial[7][r];
                float inv = rsqrtf(ssum);
                out[(long)n * HID_DIM + 16 * w + (l & 15)] = acc[mt][i] * inv;
            }
        }
}

extern "C" void kernel_launch(void* const* d_in, const int* in_sizes, int n_in,
                              void* d_out, int out_size, void* d_ws, size_t ws_size,
                              hipStream_t stream) {
    const float* h   = (const float*)d_in[0];
    const int*   src = (const int*)d_in[1];
    const int*   dst = (const int*)d_in[2];
    const float* W   = (const float*)d_in[3];
    const float* b   = (const float*)d_in[4];
    float* out = (float*)d_out;

    const int N  = N_NODES;
    const int nE = in_sizes[1];

    // workspace (~41 MB). Union region at end: binned (13.5 MB) while building,
    // then hn (25.6 MB) after p2 frees it.
    char* ws = (char*)d_ws;
    int*  lists   = (int*)ws;       ws += (size_t)NB * BCAP * 4;   // 13.5 MB
    int*  off_g   = (int*)ws;       ws += (size_t)N * 4;
    int*  degi    = (int*)ws;       ws += (size_t)N * 4;
    float* norm   = (float*)ws;     ws += (size_t)N * 4;
    int*  bcursor = (int*)ws;       ws += (size_t)(NB + 4) * 4;
    ushort* wt    = (ushort*)ws;    ws += (size_t)HID_DIM * 2 * IN_DIM * 2; // 128 KB
    char* uni     = ws;             // union region
    uint* binned  = (uint*)uni;                       // 13.5 MB
    ushort* hn    = (ushort*)uni;                     // 25.6 MB (reuses binned after p2)

    hipMemsetAsync(bcursor, 0, (size_t)NB * 4, stream);

    wconv_kernel<<<(2 * IN_DIM * HID_DIM) / 256, 256, 0, stream>>>(W, wt);

    int p1_blocks = (nE + TILE - 1) / TILE;
    p1_bin_kernel<<<p1_blocks, 256, 0, stream>>>(src, dst, bcursor, binned, nE);
    p2_fill_kernel<<<NB, 512, 0, stream>>>(binned, bcursor, lists, off_g, degi, norm, N);

    int prep_units = (N + 1) * 16;
    prep_kernel<<<(prep_units + 255) / 256, 256, 0, stream>>>(h, norm, hn, N);

    fused_kernel<<<(N + GM - 1) / GM, 512, 0, stream>>>(
        hn, lists, off_g, degi, norm, wt, b, out, N);
}

// Round 9
// 191.389 us; speedup vs baseline: 1.2198x; 1.2198x over previous
//
#include <hip/hip_runtime.h>
#include <hip/hip_fp16.h>

#define N_NODES 100000
#define IN_DIM 128
#define HID_DIM 128
#define GM 64         // nodes per block in fused gather+GEMM
#define NB 196        // buckets (512 nodes each): b = dst >> 9
#define BCAP 17200    // per-bucket edge capacity (mean 16384, +6 sigma)
#define TILE 4096     // edges per P1 tile

typedef __attribute__((ext_vector_type(8))) short bf16x8;
typedef __attribute__((ext_vector_type(4))) float f32x4;
typedef __attribute__((ext_vector_type(2))) float f32x2;

#if defined(__has_builtin)
#if __has_builtin(__builtin_amdgcn_cvt_pk_f32_fp8) && __has_builtin(__builtin_amdgcn_cvt_pk_fp8_f32)
#define HAVE_FP8CVT 1
#endif
#endif
#ifndef HAVE_FP8CVT
#define HAVE_FP8CVT 0
#endif

// gather-table scale: hn8 stores h*norm*16 as e4m3 (keeps values out of subnormal flush)
#if HAVE_FP8CVT
#define DEC_SCALE (1.0f / 16.0f)
#else
#define DEC_SCALE (256.0f / 16.0f)   // f16 bit-trick decodes value/256
#endif

__device__ inline ushort bf16rne(float x) {
    uint u = __float_as_uint(x);
    return (ushort)((u + 0x7FFFu + ((u >> 16) & 1u)) >> 16);
}

__device__ inline uint enc4_fp8(float a, float b, float c, float d) {
#if HAVE_FP8CVT
    int r = 0;
    r = __builtin_amdgcn_cvt_pk_fp8_f32(a, b, r, false);
    r = __builtin_amdgcn_cvt_pk_fp8_f32(c, d, r, true);
    return (uint)r;
#else
    float vv[4] = {a, b, c, d};
    uint out = 0;
#pragma unroll
    for (int i = 0; i < 4; i++) {
        __half hh = __float2half(vv[i] * (1.0f / 256.0f));
        ushort hb = *reinterpret_cast<ushort*>(&hh);
        uint s = ((uint)hb >> 8) & 0x80u;
        uint em = ((uint)hb >> 7) & 0x7Fu;
        em += ((uint)hb >> 6) & 1u;          // round half-up
        if (em > 0x7Eu) em = 0x7Eu;          // clamp below NaN
        out |= (s | em) << (8 * i);
    }
    return out;
#endif
}

__device__ inline void dec4_acc(uint u, float* acc) {
#if HAVE_FP8CVT
    f32x2 a0 = __builtin_amdgcn_cvt_pk_f32_fp8((int)u, false);
    f32x2 a1 = __builtin_amdgcn_cvt_pk_f32_fp8((int)u, true);
    acc[0] += a0.x; acc[1] += a0.y; acc[2] += a1.x; acc[3] += a1.y;
#else
#pragma unroll
    for (int i = 0; i < 4; i++) {
        uint byte = (u >> (8 * i)) & 0xFFu;
        ushort hb = (ushort)(((byte & 0x80u) << 8) | ((byte & 0x7Fu) << 7));
        __half hh = *reinterpret_cast<__half*>(&hb);
        acc[i] += __half2float(hh);
    }
#endif
}

// ---- P1: bin edges by dst>>9; payload packed to 4 B: src | (local_dst<<17) ----
__global__ __launch_bounds__(256) void p1_bin_kernel(
    const int* __restrict__ src, const int* __restrict__ dst,
    int* __restrict__ bcursor, uint* __restrict__ binned, int nE) {
    __shared__ uint staged[TILE];    // 16 KB
    __shared__ uchar bid[TILE];      // 4 KB
    __shared__ int cnt[256];
    __shared__ int scn[256];
    __shared__ int cur[256];
    __shared__ int gbase[256];
    int t = threadIdx.x;
    int e0 = blockIdx.x * TILE;
    int tilecnt = nE - e0; if (tilecnt > TILE) tilecnt = TILE;

    cnt[t] = 0;
    __syncthreads();

    int es[16], ed[16];
    int vk[4];
#pragma unroll
    for (int k = 0; k < 4; k++) {
        int base = e0 + (k * 256 + t) * 4;
        vk[k] = (base < nE);
        if (vk[k]) {
            int4 s4 = *(const int4*)(src + base);
            int4 d4 = *(const int4*)(dst + base);
            es[k*4+0]=s4.x; es[k*4+1]=s4.y; es[k*4+2]=s4.z; es[k*4+3]=s4.w;
            ed[k*4+0]=d4.x; ed[k*4+1]=d4.y; ed[k*4+2]=d4.z; ed[k*4+3]=d4.w;
        }
    }
#pragma unroll
    for (int k = 0; k < 4; k++)
        if (vk[k]) {
#pragma unroll
            for (int j = 0; j < 4; j++) atomicAdd(&cnt[ed[k*4+j] >> 9], 1);
        }
    __syncthreads();
    scn[t] = cnt[t];
    __syncthreads();
    for (int d = 1; d < 256; d <<= 1) {
        int v = (t >= d) ? scn[t - d] : 0;
        __syncthreads();
        scn[t] += v;
        __syncthreads();
    }
    int excl = scn[t] - cnt[t];
    __syncthreads();
    scn[t] = excl;
    cur[t] = excl;
    if (t < NB) gbase[t] = atomicAdd(&bcursor[t], cnt[t]);
    __syncthreads();
#pragma unroll
    for (int k = 0; k < 4; k++)
        if (vk[k]) {
#pragma unroll
            for (int j = 0; j < 4; j++) {
                int d = ed[k*4+j];
                int b = d >> 9;
                int r = atomicAdd(&cur[b], 1);
                staged[r] = (uint)es[k*4+j] | ((uint)(d & 511) << 17);
                bid[r] = (uchar)b;
            }
        }
    __syncthreads();
    for (int i = t; i < tilecnt; i += 256) {
        uint p = staged[i];
        int b = bid[i];
        int off = gbase[b] + (i - scn[b]);
        if (off < BCAP) binned[(long)b * BCAP + off] = p;
    }
}

// ---- P2: one block per bucket; build exact CSR in LDS; emits norm ----
__global__ __launch_bounds__(512) void p2_fill_kernel(
    const uint* __restrict__ binned, const int* __restrict__ bcursor,
    int* __restrict__ lists, int* __restrict__ off_g, int* __restrict__ degi,
    float* __restrict__ norm, int N) {
    __shared__ int deg_l[512];
    __shared__ int off_l[512];
    __shared__ int cur_l[512];
    __shared__ int stage[BCAP];   // 68.8 KB
    int b = blockIdx.x;
    int t = threadIdx.x;
    int cnt = bcursor[b]; if (cnt > BCAP) cnt = BCAP;
    const uint* eb = binned + (long)b * BCAP;
    int d0 = b << 9;

    deg_l[t] = 0;
    cur_l[t] = 0;
    __syncthreads();
    for (int i = t; i < cnt; i += 512) atomicAdd(&deg_l[eb[i] >> 17], 1);
    __syncthreads();
    off_l[t] = deg_l[t];
    __syncthreads();
    for (int d = 1; d < 512; d <<= 1) {
        int v = (t >= d) ? off_l[t - d] : 0;
        __syncthreads();
        off_l[t] += v;
        __syncthreads();
    }
    int excl = off_l[t] - deg_l[t];
    int node = d0 + t;
    if (node < N) {
        int dg = deg_l[t];
        degi[node] = dg;
        off_g[node] = b * BCAP + excl;
        norm[node] = rsqrtf((float)(dg < 1 ? 1 : dg));
    }
    __syncthreads();
    off_l[t] = excl;
    __syncthreads();
    for (int i = t; i < cnt; i += 512) {
        uint p = eb[i];
        int li = p >> 17;
        int pos = off_l[li] + atomicAdd(&cur_l[li], 1);
        stage[pos] = (int)(p & 0x1FFFFu);
    }
    __syncthreads();
    for (int i = t; i < cnt; i += 512) lists[(long)b * BCAP + i] = stage[i];
}

// ---- prep: hn8[n] = e4m3(h[n] * norm[n] * 16); row N = zeros. Thread per 8 cols ----
__global__ void prep_kernel(const float* __restrict__ h, const float* __restrict__ norm,
                            uint* __restrict__ hn8, int N) {
    int t = blockIdx.x * blockDim.x + threadIdx.x;
    int node = t >> 4;
    if (node > N) return;
    uint2 o = make_uint2(0, 0);
    if (node < N) {
        int c = (t & 15) * 8;
        float nm = norm[node] * 16.0f;
        const float* p = h + (long)node * IN_DIM + c;
        float4 a = ((const float4*)p)[0];
        float4 bb = ((const float4*)p)[1];
        o.x = enc4_fp8(a.x * nm, a.y * nm, a.z * nm, a.w * nm);
        o.y = enc4_fp8(bb.x * nm, bb.y * nm, bb.z * nm, bb.w * nm);
    }
    ((uint2*)hn8)[t] = o;
}

// ---- W [256][128] fp32 -> wt [128][256] bf16 (transposed) ----
__global__ void wconv_kernel(const float* __restrict__ W, ushort* __restrict__ wt) {
    int t = blockIdx.x * blockDim.x + threadIdx.x;  // 32768
    int j = t >> 8, k = t & 255;
    wt[t] = bf16rne(W[k * HID_DIM + j]);
}

// ---- fused gather(fp8) + MFMA GEMM + L2norm; 512 threads (8 waves), 64 nodes ----
__global__ __launch_bounds__(512) void fused_kernel(
    const float* __restrict__ h, const uint* __restrict__ hn8,
    const int* __restrict__ lists, const int* __restrict__ off_g,
    const int* __restrict__ degi, const float* __restrict__ norm,
    const ushort* __restrict__ wt, const float* __restrict__ b,
    float* __restrict__ out, int N) {
    int t = threadIdx.x;
    int w = t >> 6;
    int l = t & 63;
    int n0 = blockIdx.x * GM;

    __shared__ __align__(16) ushort rows[GM][264];  // 33.8 KB
    __shared__ float partial[8][GM];                // 2 KB

    // Phase A: stage h-half as bf16 (cols 0..127) from fp32 h
    for (int f = t; f < GM * 32; f += 512) {
        int m = f >> 5, c = (f & 31) * 4;
        int n = n0 + m;
        float4 v = make_float4(0, 0, 0, 0);
        if (n < N) v = *(const float4*)(h + (long)n * IN_DIM + c);
        ushort4 hv;
        hv.x = bf16rne(v.x); hv.y = bf16rne(v.y); hv.z = bf16rne(v.z); hv.w = bf16rne(v.w);
        *(ushort4*)&rows[m][c] = hv;
    }

    // Phase B: gather agg-half (cols 128..255); 8 nodes/wave, 8 edges in flight,
    // 8 lanes per edge row (16 B fp8 = 16 cols per lane)
    int grp = l >> 3;            // edge slot 0..7
    int c16 = (l & 7) * 16;      // fp8 column offset (16 cols)
    for (int i = 0; i < 8; i++) {
        int m = w * 8 + i;
        int node = n0 + m;
        float acc[16];
#pragma unroll
        for (int q = 0; q < 16; q++) acc[q] = 0.0f;
        int deg = 0;
        const int* mylist = lists;
        if (node < N) { deg = degi[node]; mylist = lists + off_g[node]; }
        for (int base = 0; base < deg; base += 64) {
            int cnt = deg - base; if (cnt > 64) cnt = 64;
            int myidx = (l < cnt) ? mylist[base + l] : 0;
            for (int j = 0; j < cnt; j += 8) {
                int sel = j + grp;
                int selc = sel < cnt ? sel : cnt - 1;
                int s = __shfl(myidx, selc);
                if (sel >= cnt) s = N;       // zero row
                uint4 v = *(const uint4*)((const char*)hn8 + (long)s * IN_DIM + c16);
                dec4_acc(v.x, acc + 0);
                dec4_acc(v.y, acc + 4);
                dec4_acc(v.z, acc + 8);
                dec4_acc(v.w, acc + 12);
            }
        }
#pragma unroll
        for (int q = 0; q < 16; q++) {
            acc[q] += __shfl_xor(acc[q], 8);
            acc[q] += __shfl_xor(acc[q], 16);
            acc[q] += __shfl_xor(acc[q], 32);
        }
        if (l < 8) {                 // lane l holds cols l*16..l*16+15
            float nm = (node < N) ? norm[node] * DEC_SCALE : 0.0f;
            uint rr[8];
#pragma unroll
            for (int q = 0; q < 8; q++) {
                uint lo = (uint)bf16rne(acc[2 * q] * nm);
                uint hi = (uint)bf16rne(acc[2 * q + 1] * nm);
                rr[q] = lo | (hi << 16);
            }
            uint4 o0 = make_uint4(rr[0], rr[1], rr[2], rr[3]);
            uint4 o1 = make_uint4(rr[4], rr[5], rr[6], rr[7]);
            *(uint4*)&rows[m][IN_DIM + l * 16] = o0;
            *(uint4*)&rows[m][IN_DIM + l * 16 + 8] = o1;
        }
    }

    // W slab into registers (16 cols per wave; L2-resident wt)
    bf16x8 bfrag[8];
    {
        int colA = 16 * w + (l & 15);
        int ko = (l >> 4) * 8;
#pragma unroll
        for (int kt = 0; kt < 8; kt++)
            bfrag[kt] = *(const bf16x8*)(wt + (long)colA * 256 + kt * 32 + ko);
    }

    float bj = b[16 * w + (l & 15)];
    f32x4 acc[4];
#pragma unroll
    for (int mt = 0; mt < 4; mt++) acc[mt] = (f32x4){bj, bj, bj, bj};
    __syncthreads();

    // K loop: 8 steps of 32
#pragma unroll
    for (int kt = 0; kt < 8; kt++) {
        int kbyte = kt * 64 + (l >> 4) * 16;
#pragma unroll
        for (int mt = 0; mt < 4; mt++) {
            int row = mt * 16 + (l & 15);
            bf16x8 a = *(const bf16x8*)((const char*)&rows[row][0] + kbyte);
            acc[mt] = __builtin_amdgcn_mfma_f32_16x16x32_bf16(a, bfrag[kt], acc[mt], 0, 0, 0);
        }
    }

    // per-row sum of squares within this wave's 16 cols: C/D col=l&15, row=(l>>4)*4+i
#pragma unroll
    for (int mt = 0; mt < 4; mt++)
#pragma unroll
        for (int i = 0; i < 4; i++) {
            float s = acc[mt][i] * acc[mt][i];
            s += __shfl_xor(s, 1);
            s += __shfl_xor(s, 2);
            s += __shfl_xor(s, 4);
            s += __shfl_xor(s, 8);
            if ((l & 15) == 0) partial[w][mt * 16 + (l >> 4) * 4 + i] = s;
        }
    __syncthreads();

#pragma unroll
    for (int mt = 0; mt < 4; mt++)
#pragma unroll
        for (int i = 0; i < 4; i++) {
            int r = mt * 16 + (l >> 4) * 4 + i;
            int n = n0 + r;
            if (n < N) {
                float ssum = partial[0][r] + partial[1][r] + partial[2][r] + partial[3][r]
                           + partial[4][r] + partial[5][r] + partial[6][r] + partial[7][r];
                float inv = rsqrtf(ssum);
                out[(long)n * HID_DIM + 16 * w + (l & 15)] = acc[mt][i] * inv;
            }
        }
}

extern "C" void kernel_launch(void* const* d_in, const int* in_sizes, int n_in,
                              void* d_out, int out_size, void* d_ws, size_t ws_size,
                              hipStream_t stream) {
    const float* h   = (const float*)d_in[0];
    const int*   src = (const int*)d_in[1];
    const int*   dst = (const int*)d_in[2];
    const float* W   = (const float*)d_in[3];
    const float* b   = (const float*)d_in[4];
    float* out = (float*)d_out;

    const int N  = N_NODES;
    const int nE = in_sizes[1];

    // workspace (~28.5 MB). Union region: binned (13.5 MB) while building CSR,
    // then hn8 (12.93 MB) after p2 frees it.
    char* ws = (char*)d_ws;
    int*  lists   = (int*)ws;       ws += (size_t)NB * BCAP * 4;   // 13.5 MB
    int*  off_g   = (int*)ws;       ws += (size_t)N * 4;
    int*  degi    = (int*)ws;       ws += (size_t)N * 4;
    float* norm   = (float*)ws;     ws += (size_t)N * 4;
    int*  bcursor = (int*)ws;       ws += (size_t)(NB + 4) * 4;
    ushort* wt    = (ushort*)ws;    ws += (size_t)HID_DIM * 2 * IN_DIM * 2; // 128 KB
    char* uni     = ws;
    uint* binned  = (uint*)uni;     // 13.5 MB
    uint* hn8     = (uint*)uni;     // 12.93 MB (reuses binned after p2)

    hipMemsetAsync(bcursor, 0, (size_t)NB * 4, stream);

    wconv_kernel<<<(2 * IN_DIM * HID_DIM) / 256, 256, 0, stream>>>(W, wt);

    int p1_blocks = (nE + TILE - 1) / TILE;
    p1_bin_kernel<<<p1_blocks, 256, 0, stream>>>(src, dst, bcursor, binned, nE);
    p2_fill_kernel<<<NB, 512, 0, stream>>>(binned, bcursor, lists, off_g, degi, norm, N);

    int prep_units = (N + 1) * 16;   // thread per 8 cols
    prep_kernel<<<(prep_units + 255) / 256, 256, 0, stream>>>(h, norm, hn8, N);

    fused_kernel<<<(N + GM - 1) / GM, 512, 0, stream>>>(
        h, hn8, lists, off_g, degi, norm, wt, b, out, N);
}

// Round 10
// 163.273 us; speedup vs baseline: 1.4299x; 1.1722x over previous
//
#include <hip/hip_runtime.h>
#include <hip/hip_fp16.h>

#define N_NODES 100000
#define IN_DIM 128
#define HID_DIM 128
#define GM 64         // nodes per block in fused gather+GEMM
#define NB 196        // buckets (512 nodes each): b = dst >> 9
#define BCAP 17200    // per-bucket edge capacity (mean 16384, +6 sigma)
#define TILE 4096     // edges per P1 tile
#define NR 8          // src ranges (src>>14): cache-blocked gather windows

typedef __attribute__((ext_vector_type(8))) short bf16x8;
typedef __attribute__((ext_vector_type(4))) float f32x4;
typedef __attribute__((ext_vector_type(2))) float f32x2;

#if defined(__has_builtin)
#if __has_builtin(__builtin_amdgcn_cvt_pk_f32_fp8) && __has_builtin(__builtin_amdgcn_cvt_pk_fp8_f32)
#define HAVE_FP8CVT 1
#endif
#endif
#ifndef HAVE_FP8CVT
#define HAVE_FP8CVT 0
#endif

#if HAVE_FP8CVT
#define DEC_SCALE (1.0f / 16.0f)
#else
#define DEC_SCALE (256.0f / 16.0f)
#endif

__device__ inline ushort bf16rne(float x) {
    uint u = __float_as_uint(x);
    return (ushort)((u + 0x7FFFu + ((u >> 16) & 1u)) >> 16);
}

__device__ inline uint enc4_fp8(float a, float b, float c, float d) {
#if HAVE_FP8CVT
    int r = 0;
    r = __builtin_amdgcn_cvt_pk_fp8_f32(a, b, r, false);
    r = __builtin_amdgcn_cvt_pk_fp8_f32(c, d, r, true);
    return (uint)r;
#else
    float vv[4] = {a, b, c, d};
    uint out = 0;
#pragma unroll
    for (int i = 0; i < 4; i++) {
        __half hh = __float2half(vv[i] * (1.0f / 256.0f));
        ushort hb = *reinterpret_cast<ushort*>(&hh);
        uint s = ((uint)hb >> 8) & 0x80u;
        uint em = ((uint)hb >> 7) & 0x7Fu;
        em += ((uint)hb >> 6) & 1u;
        if (em > 0x7Eu) em = 0x7Eu;
        out |= (s | em) << (8 * i);
    }
    return out;
#endif
}

__device__ inline void dec4_acc(uint u, float* acc) {
#if HAVE_FP8CVT
    f32x2 a0 = __builtin_amdgcn_cvt_pk_f32_fp8((int)u, false);
    f32x2 a1 = __builtin_amdgcn_cvt_pk_f32_fp8((int)u, true);
    acc[0] += a0.x; acc[1] += a0.y; acc[2] += a1.x; acc[3] += a1.y;
#else
#pragma unroll
    for (int i = 0; i < 4; i++) {
        uint byte = (u >> (8 * i)) & 0xFFu;
        ushort hb = (ushort)(((byte & 0x80u) << 8) | ((byte & 0x7Fu) << 7));
        __half hh = *reinterpret_cast<__half*>(&hb);
        acc[i] += __half2float(hh);
    }
#endif
}

// ---- P1: bin edges by dst>>9; payload packed to 4 B: src | (local_dst<<17) ----
__global__ __launch_bounds__(256) void p1_bin_kernel(
    const int* __restrict__ src, const int* __restrict__ dst,
    int* __restrict__ bcursor, uint* __restrict__ binned, int nE) {
    __shared__ uint staged[TILE];
    __shared__ uchar bid[TILE];
    __shared__ int cnt[256];
    __shared__ int scn[256];
    __shared__ int cur[256];
    __shared__ int gbase[256];
    int t = threadIdx.x;
    int e0 = blockIdx.x * TILE;
    int tilecnt = nE - e0; if (tilecnt > TILE) tilecnt = TILE;

    cnt[t] = 0;
    __syncthreads();

    int es[16], ed[16];
    int vk[4];
#pragma unroll
    for (int k = 0; k < 4; k++) {
        int base = e0 + (k * 256 + t) * 4;
        vk[k] = (base < nE);
        if (vk[k]) {
            int4 s4 = *(const int4*)(src + base);
            int4 d4 = *(const int4*)(dst + base);
            es[k*4+0]=s4.x; es[k*4+1]=s4.y; es[k*4+2]=s4.z; es[k*4+3]=s4.w;
            ed[k*4+0]=d4.x; ed[k*4+1]=d4.y; ed[k*4+2]=d4.z; ed[k*4+3]=d4.w;
        }
    }
#pragma unroll
    for (int k = 0; k < 4; k++)
        if (vk[k]) {
#pragma unroll
            for (int j = 0; j < 4; j++) atomicAdd(&cnt[ed[k*4+j] >> 9], 1);
        }
    __syncthreads();
    scn[t] = cnt[t];
    __syncthreads();
    for (int d = 1; d < 256; d <<= 1) {
        int v = (t >= d) ? scn[t - d] : 0;
        __syncthreads();
        scn[t] += v;
        __syncthreads();
    }
    int excl = scn[t] - cnt[t];
    __syncthreads();
    scn[t] = excl;
    cur[t] = excl;
    if (t < NB) gbase[t] = atomicAdd(&bcursor[t], cnt[t]);
    __syncthreads();
#pragma unroll
    for (int k = 0; k < 4; k++)
        if (vk[k]) {
#pragma unroll
            for (int j = 0; j < 4; j++) {
                int d = ed[k*4+j];
                int b = d >> 9;
                int r = atomicAdd(&cur[b], 1);
                staged[r] = (uint)es[k*4+j] | ((uint)(d & 511) << 17);
                bid[r] = (uchar)b;
            }
        }
    __syncthreads();
    for (int i = t; i < tilecnt; i += 256) {
        uint p = staged[i];
        int b = bid[i];
        int off = gbase[b] + (i - scn[b]);
        if (off < BCAP) binned[(long)b * BCAP + off] = p;
    }
}

// ---- P2: per-bucket CSR, segmented by (node, src-range); emits norm + off_rg ----
__global__ __launch_bounds__(512) void p2_fill_kernel(
    const uint* __restrict__ binned, const int* __restrict__ bcursor,
    int* __restrict__ lists, int* __restrict__ off_g, int* __restrict__ degi,
    float* __restrict__ norm, uchar* __restrict__ off_rg, int N) {
    __shared__ int cnt2[512 * NR];   // 16 KB: counts -> cursors
    __shared__ int off2[512 * NR];   // 16 KB: exclusive offsets
    __shared__ int temp[512];        // 2 KB
    __shared__ int stage[BCAP];      // 68.8 KB
    int b = blockIdx.x;
    int t = threadIdx.x;
    int cnt = bcursor[b]; if (cnt > BCAP) cnt = BCAP;
    const uint* eb = binned + (long)b * BCAP;
    int d0 = b << 9;

    for (int k = t; k < 512 * NR; k += 512) cnt2[k] = 0;
    __syncthreads();
    for (int i = t; i < cnt; i += 512) {
        uint p = eb[i];
        int key = (int)(p >> 17) * NR + (int)((p & 0x1FFFFu) >> 14);
        atomicAdd(&cnt2[key], 1);
    }
    __syncthreads();
    // exclusive scan over 4096: each thread owns 8 consecutive
    int base8 = t * 8;
    int loc[8];
    int s = 0;
#pragma unroll
    for (int k = 0; k < 8; k++) { int v = cnt2[base8 + k]; loc[k] = s; s += v; }
    temp[t] = s;
    __syncthreads();
    for (int d = 1; d < 512; d <<= 1) {
        int v = (t >= d) ? temp[t - d] : 0;
        __syncthreads();
        temp[t] += v;
        __syncthreads();
    }
    int tbase = (t == 0) ? 0 : temp[t - 1];
#pragma unroll
    for (int k = 0; k < 8; k++) off2[base8 + k] = tbase + loc[k];
    __syncthreads();
    // per-node outputs (thread t <-> local node t)
    {
        int node = d0 + t;
        if (node < N) {
            int S = off2[t * NR];
            int nxt = (t < 511) ? off2[t * NR + NR] : cnt;
            int dg = nxt - S;
            degi[node] = dg;
            off_g[node] = b * BCAP + S;
            norm[node] = rsqrtf((float)(dg < 1 ? 1 : dg));
            uint lo = 0, hi = 0;
#pragma unroll
            for (int r = 0; r < 4; r++) lo |= ((uint)(off2[t * NR + r] - S) & 0xFFu) << (8 * r);
#pragma unroll
            for (int r = 4; r < 8; r++) hi |= ((uint)(off2[t * NR + r] - S) & 0xFFu) << (8 * (r - 4));
            *(uint2*)(off_rg + (long)node * 8) = make_uint2(lo, hi);
        }
    }
    // reuse cnt2 as cursors
    for (int k = t; k < 512 * NR; k += 512) cnt2[k] = 0;
    __syncthreads();
    for (int i = t; i < cnt; i += 512) {
        uint p = eb[i];
        int sv = (int)(p & 0x1FFFFu);
        int key = (int)(p >> 17) * NR + (sv >> 14);
        int pos = off2[key] + atomicAdd(&cnt2[key], 1);
        stage[pos] = sv;
    }
    __syncthreads();
    for (int i = t; i < cnt; i += 512) lists[(long)b * BCAP + i] = stage[i];
}

// ---- prep: hn8[n] = e4m3(h*norm*16); hbf[n] = bf16(h); row N of hn8 = zeros ----
__global__ void prep_kernel(const float* __restrict__ h, const float* __restrict__ norm,
                            uint* __restrict__ hn8, ushort* __restrict__ hbf, int N) {
    int t = blockIdx.x * blockDim.x + threadIdx.x;
    int node = t >> 4;
    if (node > N) return;
    uint2 o = make_uint2(0, 0);
    if (node < N) {
        int c = (t & 15) * 8;
        float nm = norm[node] * 16.0f;
        const float* p = h + (long)node * IN_DIM + c;
        float4 a = ((const float4*)p)[0];
        float4 bb = ((const float4*)p)[1];
        o.x = enc4_fp8(a.x * nm, a.y * nm, a.z * nm, a.w * nm);
        o.y = enc4_fp8(bb.x * nm, bb.y * nm, bb.z * nm, bb.w * nm);
        uint4 hb;
        hb.x = (uint)bf16rne(a.x)  | ((uint)bf16rne(a.y) << 16);
        hb.y = (uint)bf16rne(a.z)  | ((uint)bf16rne(a.w) << 16);
        hb.z = (uint)bf16rne(bb.x) | ((uint)bf16rne(bb.y) << 16);
        hb.w = (uint)bf16rne(bb.z) | ((uint)bf16rne(bb.w) << 16);
        *(uint4*)(hbf + (long)node * IN_DIM + c) = hb;
    }
    ((uint2*)hn8)[t] = o;
}

// ---- W [256][128] fp32 -> wt [128][256] bf16 (transposed) ----
__global__ void wconv_kernel(const float* __restrict__ W, ushort* __restrict__ wt) {
    int t = blockIdx.x * blockDim.x + threadIdx.x;
    int j = t >> 8, k = t & 255;
    wt[t] = bf16rne(W[k * HID_DIM + j]);
}

// ---- fused range-synced gather(fp8) + MFMA GEMM + L2norm; 512 threads, 64 nodes ----
// Phase B: lane (g=l>>3, sub=l&7): slot g owns node w*8+g, 16 fp8 cols at sub*16.
__global__ __launch_bounds__(512) void fused_kernel(
    const ushort* __restrict__ hbf, const uint* __restrict__ hn8,
    const int* __restrict__ lists, const int* __restrict__ off_g,
    const int* __restrict__ degi, const float* __restrict__ norm,
    const uchar* __restrict__ off_rg, const ushort* __restrict__ wt,
    const float* __restrict__ bias, float* __restrict__ out, int N) {
    int t = threadIdx.x;
    int w = t >> 6;
    int l = t & 63;
    int n0 = blockIdx.x * GM;

    __shared__ __align__(16) ushort rows[GM][264];  // 33.8 KB
    __shared__ float partial[8][GM];                // 2 KB

    // Phase A: h-half (cols 0..127) straight copy from bf16 hbf
    for (int f = t; f < GM * 16; f += 512) {
        int m = f >> 4, c = (f & 15) * 8;
        int n = n0 + m;
        uint4 v = make_uint4(0, 0, 0, 0);
        if (n < N) v = *(const uint4*)(hbf + (long)n * IN_DIM + c);
        *(uint4*)&rows[m][c] = v;
    }

    // Phase B: range-synced gather
    {
        int g = l >> 3, sub = l & 7;
        int m = w * 8 + g;
        int node = n0 + m;
        bool valid = node < N;
        int deg = valid ? degi[node] : 0;
        int S = valid ? off_g[node] : 0;
        uint2 rsw = make_uint2(0, 0);
        if (valid) rsw = *(const uint2*)(off_rg + (long)node * 8);
        float acc[16];
#pragma unroll
        for (int q = 0; q < 16; q++) acc[q] = 0.0f;
        const char* rowbase = (const char*)hn8;
        int c16 = sub * 16;
        int st = 0;
#pragma unroll
        for (int r = 0; r < NR; r++) {
            int en = (r < 7)
                ? (int)((r + 1 < 4 ? (rsw.x >> (8 * (r + 1))) : (rsw.y >> (8 * (r - 3)))) & 0xFFu)
                : deg;
            int len = en - st;
            int mx = len;
            mx = max(mx, __shfl_xor(mx, 8));
            mx = max(mx, __shfl_xor(mx, 16));
            mx = max(mx, __shfl_xor(mx, 32));
            for (int base = 0; base < mx; base += 8) {
                int myidx = (sub < len - base) ? lists[S + st + base + sub] : 0;
                int kmax = mx - base; if (kmax > 8) kmax = 8;
                for (int k = 0; k < kmax; k++) {
                    int s2 = __shfl(myidx, (g << 3) | k);
                    if (base + k >= len) s2 = N;   // zero row
                    uint4 v = *(const uint4*)(rowbase + (long)s2 * IN_DIM + c16);
                    dec4_acc(v.x, acc + 0);
                    dec4_acc(v.y, acc + 4);
                    dec4_acc(v.z, acc + 8);
                    dec4_acc(v.w, acc + 12);
                }
            }
            st = en;
        }
        // write agg-half: lane holds node m cols sub*16..sub*16+15, no reduce needed
        float nm = valid ? norm[node] * DEC_SCALE : 0.0f;
        uint rr[8];
#pragma unroll
        for (int q = 0; q < 8; q++) {
            uint lo = (uint)bf16rne(acc[2 * q] * nm);
            uint hi = (uint)bf16rne(acc[2 * q + 1] * nm);
            rr[q] = lo | (hi << 16);
        }
        *(uint4*)&rows[m][IN_DIM + c16] = make_uint4(rr[0], rr[1], rr[2], rr[3]);
        *(uint4*)&rows[m][IN_DIM + c16 + 8] = make_uint4(rr[4], rr[5], rr[6], rr[7]);
    }

    // W slab into registers (16 cols per wave; L2-resident wt)
    bf16x8 bfrag[8];
    {
        int colA = 16 * w + (l & 15);
        int ko = (l >> 4) * 8;
#pragma unroll
        for (int kt = 0; kt < 8; kt++)
            bfrag[kt] = *(const bf16x8*)(wt + (long)colA * 256 + kt * 32 + ko);
    }

    float bj = bias[16 * w + (l & 15)];
    f32x4 cacc[4];
#pragma unroll
    for (int mt = 0; mt < 4; mt++) cacc[mt] = (f32x4){bj, bj, bj, bj};
    __syncthreads();

    // K loop: 8 steps of 32
#pragma unroll
    for (int kt = 0; kt < 8; kt++) {
        int kbyte = kt * 64 + (l >> 4) * 16;
#pragma unroll
        for (int mt = 0; mt < 4; mt++) {
            int row = mt * 16 + (l & 15);
            bf16x8 a = *(const bf16x8*)((const char*)&rows[row][0] + kbyte);
            cacc[mt] = __builtin_amdgcn_mfma_f32_16x16x32_bf16(a, bfrag[kt], cacc[mt], 0, 0, 0);
        }
    }

    // per-row sum of squares: C/D col=l&15, row=(l>>4)*4+i
#pragma unroll
    for (int mt = 0; mt < 4; mt++)
#pragma unroll
        for (int i = 0; i < 4; i++) {
            float s = cacc[mt][i] * cacc[mt][i];
            s += __shfl_xor(s, 1);
            s += __shfl_xor(s, 2);
            s += __shfl_xor(s, 4);
            s += __shfl_xor(s, 8);
            if ((l & 15) == 0) partial[w][mt * 16 + (l >> 4) * 4 + i] = s;
        }
    __syncthreads();

#pragma unroll
    for (int mt = 0; mt < 4; mt++)
#pragma unroll
        for (int i = 0; i < 4; i++) {
            int r = mt * 16 + (l >> 4) * 4 + i;
            int n = n0 + r;
            if (n < N) {
                float ssum = partial[0][r] + partial[1][r] + partial[2][r] + partial[3][r]
                           + partial[4][r] + partial[5][r] + partial[6][r] + partial[7][r];
                float inv = rsqrtf(ssum);
                out[(long)n * HID_DIM + 16 * w + (l & 15)] = cacc[mt][i] * inv;
            }
        }
}

extern "C" void kernel_launch(void* const* d_in, const int* in_sizes, int n_in,
                              void* d_out, int out_size, void* d_ws, size_t ws_size,
                              hipStream_t stream) {
    const float* h   = (const float*)d_in[0];
    const int*   src = (const int*)d_in[1];
    const int*   dst = (const int*)d_in[2];
    const float* W   = (const float*)d_in[3];
    const float* b   = (const float*)d_in[4];
    float* out = (float*)d_out;

    const int N  = N_NODES;
    const int nE = in_sizes[1];

    // workspace (~55 MB). Union region: binned (13.5 MB) while building CSR,
    // then hn8 (12.93 MB) after p2 frees it. hbf is separate (live with hn8).
    char* ws = (char*)d_ws;
    int*  lists   = (int*)ws;       ws += (size_t)NB * BCAP * 4;   // 13.5 MB
    int*  off_g   = (int*)ws;       ws += (size_t)N * 4;
    int*  degi    = (int*)ws;       ws += (size_t)N * 4;
    float* norm   = (float*)ws;     ws += (size_t)N * 4;
    int*  bcursor = (int*)ws;       ws += (size_t)(NB + 4) * 4;
    ushort* wt    = (ushort*)ws;    ws += (size_t)HID_DIM * 2 * IN_DIM * 2; // 128 KB
    uchar* off_rg = (uchar*)ws;     ws += (size_t)N * 8;           // 0.8 MB
    ushort* hbf   = (ushort*)ws;    ws += (size_t)N * IN_DIM * 2;  // 25.6 MB
    char* uni     = ws;
    uint* binned  = (uint*)uni;     // 13.5 MB
    uint* hn8     = (uint*)uni;     // 12.93 MB (reuses binned after p2)

    hipMemsetAsync(bcursor, 0, (size_t)NB * 4, stream);

    wconv_kernel<<<(2 * IN_DIM * HID_DIM) / 256, 256, 0, stream>>>(W, wt);

    int p1_blocks = (nE + TILE - 1) / TILE;
    p1_bin_kernel<<<p1_blocks, 256, 0, stream>>>(src, dst, bcursor, binned, nE);
    p2_fill_kernel<<<NB, 512, 0, stream>>>(binned, bcursor, lists, off_g, degi, norm, off_rg, N);

    int prep_units = (N + 1) * 16;
    prep_kernel<<<(prep_units + 255) / 256, 256, 0, stream>>>(h, norm, hn8, hbf, N);

    fused_kernel<<<(N + GM - 1) / GM, 512, 0, stream>>>(
        hbf, hn8, lists, off_g, degi, norm, off_rg, wt, b, out, N);
}